// Round 1
// baseline (116.874 us; speedup 1.0000x reference)
//
#include <hip/hip_runtime.h>

// SimpleMatcher: B=128, N=900 preds, T=300 targets.
// out = [pred_idx (B*T floats), valid (B*T floats 0/1), max_iou (B*T floats)]
//
// Correctness strategy: GIoU computed with IEEE ops in EXACTLY numpy's
// expression order (fp contract off, exact f32 division) so argmax matches
// the numpy reference bit-for-bit (first-occurrence tie-break preserved).

#define BB 128
#define NN 900
#define TT 300
#define TCHUNK 64      // targets per block
#define NGROUPS 4      // n-slices (one per wave)
#define NSLICE 225     // NN / NGROUPS
#define TBLOCKS 5      // ceil(TT / TCHUNK)

__global__ __launch_bounds__(256) void simple_matcher_kernel(
    const float* __restrict__ pred,          // [B,N,4] cxcywh
    const float* __restrict__ tgt,           // [B,T,4] cxcywh
    const unsigned char* __restrict__ mask,  // [B,T] bool (1 byte)
    float* __restrict__ out)                 // [3, B*T]
{
#pragma clang fp contract(off)
    __shared__ float spx0[NN], spy0[NN], spx1[NN], spy1[NN], spa[NN];
    __shared__ float sbest[256];
    __shared__ int   sbidx[256];

    const int b   = blockIdx.x / TBLOCKS;
    const int tc  = blockIdx.x % TBLOCKS;
    const int tid = threadIdx.x;
    const int tl  = tid & 63;   // target lane within chunk
    const int ng  = tid >> 6;   // n-slice (wave id), 0..3
    const int t   = tc * TCHUNK + tl;

    // ---- stage pred boxes for batch b into LDS as xyxy + area ----
    for (int i = tid; i < NN; i += 256) {
        const float4 pb = ((const float4*)pred)[b * NN + i];
        float x0 = pb.x - 0.5f * pb.z;
        float y0 = pb.y - 0.5f * pb.w;
        float x1 = pb.x + 0.5f * pb.z;
        float y1 = pb.y + 0.5f * pb.w;
        spx0[i] = x0; spy0[i] = y0; spx1[i] = x1; spy1[i] = y1;
        spa[i]  = (x1 - x0) * (y1 - y0);
    }
    __syncthreads();

    // ---- per-thread target box (xyxy + area), exact like reference ----
    float tx0 = 0.f, ty0 = 0.f, tx1 = 0.f, ty1 = 0.f, ta = 0.f;
    if (t < TT) {
        const float4 tb = ((const float4*)tgt)[b * TT + t];
        tx0 = tb.x - 0.5f * tb.z;
        ty0 = tb.y - 0.5f * tb.w;
        tx1 = tb.x + 0.5f * tb.z;
        ty1 = tb.y + 0.5f * tb.w;
        ta  = (tx1 - tx0) * (ty1 - ty0);
    }

    // ---- scan this wave's pred slice; exact IEEE GIoU per numpy order ----
    float best = -INFINITY;
    int   bidx = 0;
    const int n0 = ng * NSLICE;
    for (int k = 0; k < NSLICE; ++k) {
        const int n = n0 + k;
        const float px0 = spx0[n], py0 = spy0[n];
        const float px1 = spx1[n], py1 = spy1[n];
        const float pa  = spa[n];

        const float ltx = fmaxf(px0, tx0);
        const float lty = fmaxf(py0, ty0);
        const float rbx = fminf(px1, tx1);
        const float rby = fminf(py1, ty1);
        const float w   = fmaxf(rbx - ltx, 0.f);
        const float h   = fmaxf(rby - lty, 0.f);
        const float inter = w * h;
        const float uni   = pa + ta - inter;   // (pa + ta) - inter, no FMA
        const float iou   = inter / uni;       // exact IEEE division

        const float ex0 = fminf(px0, tx0);
        const float ey0 = fminf(py0, ty0);
        const float ex1 = fmaxf(px1, tx1);
        const float ey1 = fmaxf(py1, ty1);
        const float ew  = fmaxf(ex1 - ex0, 0.f);
        const float eh  = fmaxf(ey1 - ey0, 0.f);
        const float ea  = ew * eh;
        const float g   = iou - (ea - uni) / ea;  // exact IEEE division

        if (g > best) { best = g; bidx = n; }  // strict >: first-occurrence
    }

    sbest[tid] = best;
    sbidx[tid] = bidx;
    __syncthreads();

    // ---- wave 0 reduces across the 4 slices (ascending slice = numpy order) ----
    if (ng == 0 && t < TT) {
        for (int s = 1; s < NGROUPS; ++s) {
            const float v = sbest[s * 64 + tl];
            const int   i = sbidx[s * 64 + tl];
            if (v > best) { best = v; bidx = i; }
        }
        const int bt = b * TT + t;
        const bool valid = (mask[bt] != 0) && (best >= 0.5f);
        out[bt]              = (float)bidx;
        out[BB * TT + bt]    = valid ? 1.f : 0.f;
        out[2 * BB * TT + bt] = best;
    }
}

extern "C" void kernel_launch(void* const* d_in, const int* in_sizes, int n_in,
                              void* d_out, int out_size, void* d_ws, size_t ws_size,
                              hipStream_t stream) {
    const float* pred = (const float*)d_in[0];
    const float* tgt  = (const float*)d_in[1];
    const unsigned char* mask = (const unsigned char*)d_in[2];
    float* out = (float*)d_out;

    dim3 grid(BB * TBLOCKS);
    dim3 block(256);
    simple_matcher_kernel<<<grid, block, 0, stream>>>(pred, tgt, mask, out);
}

// Round 2
// 111.027 us; speedup vs baseline: 1.0527x; 1.0527x over previous
//
#include <hip/hip_runtime.h>

// SimpleMatcher: B=128, N=900 preds, T=300 targets.
// out = [pred_idx (B*T floats), valid (B*T floats 0/1), max_iou (B*T floats)]
//
// GIoU computed with IEEE ops in EXACTLY numpy's expression order
// (fp contract off, correctly-rounded f32 division) so the argmax matches
// the numpy reference bit-for-bit (first-occurrence tie-break preserved
// by reducing in ascending-n order with strict >).
//
// R2: split N across 5 blocks (grid 3200, 32 waves/CU resident) + float4
// LDS pred layout (1 ds_read_b128/iter). Partials in d_ws, reduce kernel 2.

#define BB 128
#define NN 900
#define TT 300
#define TCHUNK 64      // targets per block (64 lanes)
#define TBLOCKS 5      // ceil(TT / TCHUNK)
#define NSPLIT 5       // n-splits across blocks
#define NPB 180        // preds per block  (NN / NSPLIT)
#define NPW 45         // preds per wave   (NPB / 4)

__global__ __launch_bounds__(256) void matcher_scan_kernel(
    const float* __restrict__ pred,          // [B,N,4] cxcywh
    const float* __restrict__ tgt,           // [B,T,4] cxcywh
    float2* __restrict__ part)               // [B*T][NSPLIT] (best, idx-bits)
{
#pragma clang fp contract(off)
    __shared__ float4 sp[NPB];               // pred xyxy
    __shared__ float  sbest[256];
    __shared__ int    sbidx[256];

    const int ns  = blockIdx.x % NSPLIT;
    const int tc  = (blockIdx.x / NSPLIT) % TBLOCKS;
    const int b   = blockIdx.x / (NSPLIT * TBLOCKS);
    const int tid = threadIdx.x;
    const int tl  = tid & 63;   // target lane
    const int ng  = tid >> 6;   // wave id, 0..3
    const int t   = tc * TCHUNK + tl;

    // ---- stage this block's 180 pred boxes (xyxy) into LDS ----
    if (tid < NPB) {
        const float4 pb = ((const float4*)pred)[b * NN + ns * NPB + tid];
        float4 q;
        q.x = pb.x - 0.5f * pb.z;
        q.y = pb.y - 0.5f * pb.w;
        q.z = pb.x + 0.5f * pb.z;
        q.w = pb.y + 0.5f * pb.w;
        sp[tid] = q;
    }
    __syncthreads();

    // ---- per-lane target box (xyxy + area), exact like reference ----
    float tx0 = 0.f, ty0 = 0.f, tx1 = 0.f, ty1 = 0.f, ta = 0.f;
    if (t < TT) {
        const float4 tb = ((const float4*)tgt)[b * TT + t];
        tx0 = tb.x - 0.5f * tb.z;
        ty0 = tb.y - 0.5f * tb.w;
        tx1 = tb.x + 0.5f * tb.z;
        ty1 = tb.y + 0.5f * tb.w;
        ta  = (tx1 - tx0) * (ty1 - ty0);
    }

    // ---- scan this wave's 45-pred slice; exact IEEE GIoU, numpy order ----
    float best = -INFINITY;
    int   bidx = 0;
    const int k0 = ng * NPW;
    for (int k = 0; k < NPW; ++k) {
        const float4 p = sp[k0 + k];
        const float pa = (p.z - p.x) * (p.w - p.y);

        const float w   = fmaxf(fminf(p.z, tx1) - fmaxf(p.x, tx0), 0.f);
        const float h   = fmaxf(fminf(p.w, ty1) - fmaxf(p.y, ty0), 0.f);
        const float inter = w * h;
        const float uni   = pa + ta - inter;
        const float iou   = inter / uni;        // exact IEEE division

        const float ew  = fmaxf(fmaxf(p.z, tx1) - fminf(p.x, tx0), 0.f);
        const float eh  = fmaxf(fmaxf(p.w, ty1) - fminf(p.y, ty0), 0.f);
        const float ea  = ew * eh;
        const float g   = iou - (ea - uni) / ea; // exact IEEE division

        if (g > best) { best = g; bidx = k0 + k; }  // strict >: first occurrence
    }

    sbest[tid] = best;
    sbidx[tid] = bidx;
    __syncthreads();

    // ---- wave 0 reduces across the 4 waves (ascending ng = ascending n) ----
    if (ng == 0 && t < TT) {
        for (int s = 1; s < 4; ++s) {
            const float v = sbest[s * 64 + tl];
            const int   i = sbidx[s * 64 + tl];
            if (v > best) { best = v; bidx = i; }
        }
        float2 pr;
        pr.x = best;
        pr.y = __int_as_float(ns * NPB + bidx);  // global pred index
        part[(b * TT + t) * NSPLIT + ns] = pr;
    }
}

__global__ __launch_bounds__(256) void matcher_reduce_kernel(
    const float2* __restrict__ part,         // [B*T][NSPLIT]
    const unsigned char* __restrict__ mask,  // [B,T] bool
    float* __restrict__ out)                 // [3, B*T]
{
    const int bt = blockIdx.x * 256 + threadIdx.x;
    if (bt >= BB * TT) return;

    float best = -INFINITY;
    int   bidx = 0;
    for (int s = 0; s < NSPLIT; ++s) {       // ascending ns = ascending n
        const float2 pr = part[bt * NSPLIT + s];
        if (pr.x > best) { best = pr.x; bidx = __float_as_int(pr.y); }
    }
    const bool valid = (mask[bt] != 0) && (best >= 0.5f);
    out[bt]               = (float)bidx;
    out[BB * TT + bt]     = valid ? 1.f : 0.f;
    out[2 * BB * TT + bt] = best;
}

extern "C" void kernel_launch(void* const* d_in, const int* in_sizes, int n_in,
                              void* d_out, int out_size, void* d_ws, size_t ws_size,
                              hipStream_t stream) {
    const float* pred = (const float*)d_in[0];
    const float* tgt  = (const float*)d_in[1];
    const unsigned char* mask = (const unsigned char*)d_in[2];
    float* out = (float*)d_out;
    float2* part = (float2*)d_ws;            // BB*TT*NSPLIT*8 = 1.536 MB

    matcher_scan_kernel<<<dim3(BB * TBLOCKS * NSPLIT), dim3(256), 0, stream>>>(
        pred, tgt, part);
    matcher_reduce_kernel<<<dim3((BB * TT + 255) / 256), dim3(256), 0, stream>>>(
        part, mask, out);
}

// Round 3
// 107.676 us; speedup vs baseline: 1.0854x; 1.0311x over previous
//
#include <hip/hip_runtime.h>

// SimpleMatcher: B=128, N=900 preds, T=300 targets.
// out = [pred_idx (B*T), valid (B*T), max_iou (B*T)] as float.
//
// R3 strategy: scan with FAST divides (rcp + 1 Newton step, rel err ~2 ulp)
// while tracking top-2 per target. If best-second > MARGIN (1e-5 >> 2x err
// bound ~8e-7), the approx argmax provably equals the exact argmax; the
// winner's GIoU is then recomputed with bit-exact IEEE ops (numpy op order,
// contract off) for the max_iou/valid outputs. Ambiguous targets (~1%) are
// compacted and exhaustively rescanned exactly, one wave per target, with
// numpy first-occurrence tie-break.

#define BB 128
#define NN 900
#define TT 300
#define TCHUNK 64      // targets per block (64 lanes)
#define TBLOCKS 5      // ceil(TT / TCHUNK)
#define NSPLIT 5       // n-splits across blocks
#define NPB 180        // preds per block
#define NPW 45         // preds per wave
#define MARGIN 1e-5f

__device__ __forceinline__ float fdiv_fast(float n, float d) {
    float r = __builtin_amdgcn_rcpf(d);   // ~1 ulp
    float q = n * r;
    float e = fmaf(-d, q, n);
    return fmaf(e, r, q);                 // ~1 ulp final
}

// Bit-exact GIoU in numpy's exact expression order.
__device__ __forceinline__ float giou_exact(float4 pb, float4 tb) {
#pragma clang fp contract(off)
    float px0 = pb.x - 0.5f * pb.z, py0 = pb.y - 0.5f * pb.w;
    float px1 = pb.x + 0.5f * pb.z, py1 = pb.y + 0.5f * pb.w;
    float tx0 = tb.x - 0.5f * tb.z, ty0 = tb.y - 0.5f * tb.w;
    float tx1 = tb.x + 0.5f * tb.z, ty1 = tb.y + 0.5f * tb.w;
    float pa = (px1 - px0) * (py1 - py0);
    float ta = (tx1 - tx0) * (ty1 - ty0);
    float w  = fmaxf(fminf(px1, tx1) - fmaxf(px0, tx0), 0.f);
    float h  = fmaxf(fminf(py1, ty1) - fmaxf(py0, ty0), 0.f);
    float inter = w * h;
    float uni   = pa + ta - inter;
    float iou   = inter / uni;            // correctly-rounded IEEE div
    float ew = fmaxf(fmaxf(px1, tx1) - fminf(px0, tx0), 0.f);
    float eh = fmaxf(fmaxf(py1, ty1) - fminf(py0, ty0), 0.f);
    float ea = ew * eh;
    return iou - (ea - uni) / ea;         // correctly-rounded IEEE div
}

__global__ __launch_bounds__(256) void matcher_scan_kernel(
    const float* __restrict__ pred,       // [B,N,4] cxcywh
    const float* __restrict__ tgt,        // [B,T,4] cxcywh
    float* __restrict__ pbest,            // [NSPLIT][B*T]
    float* __restrict__ psec,             // [NSPLIT][B*T]
    int*   __restrict__ pidx)             // [NSPLIT][B*T]
{
    __shared__ float4 sp[NPB];            // pred xyxy
    __shared__ float  spa[NPB];           // pred area
    __shared__ float  rbv[256], rsv[256];
    __shared__ int    riv[256];

    const int ns  = blockIdx.x % NSPLIT;
    const int tc  = (blockIdx.x / NSPLIT) % TBLOCKS;
    const int b   = blockIdx.x / (NSPLIT * TBLOCKS);
    const int tid = threadIdx.x;
    const int tl  = tid & 63;
    const int ng  = tid >> 6;
    const int t   = tc * TCHUNK + tl;

    if (tid < NPB) {
        const float4 pb = ((const float4*)pred)[b * NN + ns * NPB + tid];
        float4 q;
        q.x = pb.x - 0.5f * pb.z;
        q.y = pb.y - 0.5f * pb.w;
        q.z = pb.x + 0.5f * pb.z;
        q.w = pb.y + 0.5f * pb.w;
        sp[tid]  = q;
        spa[tid] = (q.z - q.x) * (q.w - q.y);
    }
    __syncthreads();

    float tx0 = 0.f, ty0 = 0.f, tx1 = 0.f, ty1 = 0.f, ta = 0.f;
    if (t < TT) {
        const float4 tb = ((const float4*)tgt)[b * TT + t];
        tx0 = tb.x - 0.5f * tb.z;
        ty0 = tb.y - 0.5f * tb.w;
        tx1 = tb.x + 0.5f * tb.z;
        ty1 = tb.y + 0.5f * tb.w;
        ta  = (tx1 - tx0) * (ty1 - ty0);
    }

    float best = -INFINITY, second = -INFINITY;
    int   bidx = 0;
    const int k0 = ng * NPW;
    #pragma unroll 5
    for (int k = 0; k < NPW; ++k) {
        const float4 p = sp[k0 + k];      // wave-uniform -> LDS broadcast
        const float pa = spa[k0 + k];

        const float w   = fmaxf(fminf(p.z, tx1) - fmaxf(p.x, tx0), 0.f);
        const float h   = fmaxf(fminf(p.w, ty1) - fmaxf(p.y, ty0), 0.f);
        const float inter = w * h;
        const float uni   = pa + ta - inter;
        const float iou   = fdiv_fast(inter, uni);

        const float ew = fmaxf(fmaxf(p.z, tx1) - fminf(p.x, tx0), 0.f);
        const float eh = fmaxf(fmaxf(p.w, ty1) - fminf(p.y, ty0), 0.f);
        const float ea = ew * eh;
        const float g  = iou - fdiv_fast(ea - uni, ea);

        second = __builtin_amdgcn_fmed3f(g, best, second);  // new 2nd-max
        if (g > best) { bidx = k0 + k; }
        best = fmaxf(best, g);
    }

    rbv[tid] = best; rsv[tid] = second; riv[tid] = bidx;
    __syncthreads();

    if (ng == 0 && t < TT) {
        for (int s = 1; s < 4; ++s) {     // ascending wave = ascending n
            const float ob = rbv[s * 64 + tl];
            const float os = rsv[s * 64 + tl];
            const int   oi = riv[s * 64 + tl];
            second = fmaxf(fminf(best, ob), fmaxf(second, os));
            if (ob > best) { best = ob; bidx = oi; }
        }
        const int bt = b * TT + t;
        pbest[ns * BB * TT + bt] = best;
        psec [ns * BB * TT + bt] = second;
        pidx [ns * BB * TT + bt] = ns * NPB + bidx;   // global pred index
    }
}

__global__ __launch_bounds__(256) void matcher_combine_kernel(
    const float* __restrict__ pbest,
    const float* __restrict__ psec,
    const int*   __restrict__ pidx,
    const float* __restrict__ pred,
    const float* __restrict__ tgt,
    const unsigned char* __restrict__ mask,
    float* __restrict__ out,
    int*   __restrict__ counter,
    int*   __restrict__ flagged)
{
    const int bt = blockIdx.x * 256 + threadIdx.x;
    if (bt >= BB * TT) return;

    float best = -INFINITY, second = -INFINITY;
    int   bidx = 0;
    for (int s = 0; s < NSPLIT; ++s) {    // ascending ns = ascending n
        const float ob = pbest[s * BB * TT + bt];
        const float os = psec [s * BB * TT + bt];
        const int   oi = pidx [s * BB * TT + bt];
        second = fmaxf(fminf(best, ob), fmaxf(second, os));
        if (ob > best) { best = ob; bidx = oi; }
    }

    if (best - second > MARGIN) {
        // approx argmax provably exact; recompute winner's GIoU bit-exactly
        const int b = bt / TT;
        const float4 pb = ((const float4*)pred)[b * NN + bidx];
        const float4 tb = ((const float4*)tgt)[bt];
        const float g = giou_exact(pb, tb);
        const bool valid = (mask[bt] != 0) && (g >= 0.5f);
        out[bt]               = (float)bidx;
        out[BB * TT + bt]     = valid ? 1.f : 0.f;
        out[2 * BB * TT + bt] = g;
    } else {
        const int pos = atomicAdd(counter, 1);
        flagged[pos] = bt;
    }
}

__global__ __launch_bounds__(256) void matcher_rescan_kernel(
    const float* __restrict__ pred,
    const float* __restrict__ tgt,
    const unsigned char* __restrict__ mask,
    const int*   __restrict__ counter,
    const int*   __restrict__ flagged,
    float* __restrict__ out)
{
    const int wave   = (blockIdx.x * 256 + threadIdx.x) >> 6;
    const int lane   = threadIdx.x & 63;
    const int nwaves = gridDim.x * 4;
    const int cnt    = *counter;

    for (int f = wave; f < cnt; f += nwaves) {
        const int bt = flagged[f];
        const int b  = bt / TT;
        const float4 tb = ((const float4*)tgt)[bt];

        float best = -INFINITY;
        int   bidx = NN;
        for (int n = lane; n < NN; n += 64) {   // ascending n per lane
            const float4 pb = ((const float4*)pred)[b * NN + n];
            const float g = giou_exact(pb, tb);
            if (g > best) { best = g; bidx = n; }
        }
        // cross-lane reduce: max g, lowest n on bit-ties (numpy first-occ.)
        for (int off = 32; off >= 1; off >>= 1) {
            const float ob = __shfl_xor(best, off);
            const int   oi = __shfl_xor(bidx, off);
            if (ob > best || (ob == best && oi < bidx)) { best = ob; bidx = oi; }
        }
        if (lane == 0) {
            const bool valid = (mask[bt] != 0) && (best >= 0.5f);
            out[bt]               = (float)bidx;
            out[BB * TT + bt]     = valid ? 1.f : 0.f;
            out[2 * BB * TT + bt] = best;
        }
    }
}

extern "C" void kernel_launch(void* const* d_in, const int* in_sizes, int n_in,
                              void* d_out, int out_size, void* d_ws, size_t ws_size,
                              hipStream_t stream) {
    const float* pred = (const float*)d_in[0];
    const float* tgt  = (const float*)d_in[1];
    const unsigned char* mask = (const unsigned char*)d_in[2];
    float* out = (float*)d_out;

    char* ws = (char*)d_ws;
    int*   counter = (int*)ws;                                  // 4 B
    int*   flagged = (int*)(ws + 64);                           // 150 KB
    float* pbest   = (float*)(ws + 64 + BB * TT * 4);           // 750 KB
    float* psec    = (float*)(ws + 64 + BB * TT * 4 * 6);       // 750 KB
    int*   pidx    = (int*)  (ws + 64 + BB * TT * 4 * 11);      // 750 KB
    // total ~2.4 MB

    hipMemsetAsync(counter, 0, sizeof(int), stream);
    matcher_scan_kernel<<<dim3(BB * TBLOCKS * NSPLIT), dim3(256), 0, stream>>>(
        pred, tgt, pbest, psec, pidx);
    matcher_combine_kernel<<<dim3((BB * TT + 255) / 256), dim3(256), 0, stream>>>(
        pbest, psec, pidx, pred, tgt, mask, out, counter, flagged);
    matcher_rescan_kernel<<<dim3(64), dim3(256), 0, stream>>>(
        pred, tgt, mask, counter, flagged, out);
}

// Round 4
// 95.581 us; speedup vs baseline: 1.2228x; 1.1265x over previous
//
#include <hip/hip_runtime.h>

// SimpleMatcher: B=128, N=900 preds, T=300 targets.
// out = [pred_idx (B*T), valid (B*T), max_iou (B*T)] as float.
//
// R4: scan uses SINGLE fast division:
//   g = inter/uni - (ea-uni)/ea = (inter*ea + uni*(uni-ea)) / (uni*ea)
// with raw v_rcp (abs err <= ~3e-7 since ea >= union >= all terms).
// Top-2 tracked per target; if best-second > MARGIN (2e-5 >> 2*err), approx
// argmax provably equals exact argmax -> recompute winner bit-exactly.
// Ambiguous targets handled in the fused finish kernel with exact IEEE math
// and numpy first-occurrence tie-break. Epilogue fused into ONE kernel
// (block-local LDS flagged list; no global counter, no memset).

#define BB 128
#define NN 900
#define TT 300
#define TCHUNK 64      // targets per block (64 lanes)
#define TBLOCKS 5      // ceil(TT / TCHUNK)
#define NSPLIT 9       // n-splits across blocks
#define NPB 100        // preds per block  (NN / NSPLIT)
#define NPW 25         // preds per wave   (NPB / 4)
#define MARGIN 2e-5f

// Bit-exact GIoU in numpy's exact expression order.
__device__ __forceinline__ float giou_exact(float4 pb, float4 tb) {
#pragma clang fp contract(off)
    float px0 = pb.x - 0.5f * pb.z, py0 = pb.y - 0.5f * pb.w;
    float px1 = pb.x + 0.5f * pb.z, py1 = pb.y + 0.5f * pb.w;
    float tx0 = tb.x - 0.5f * tb.z, ty0 = tb.y - 0.5f * tb.w;
    float tx1 = tb.x + 0.5f * tb.z, ty1 = tb.y + 0.5f * tb.w;
    float pa = (px1 - px0) * (py1 - py0);
    float ta = (tx1 - tx0) * (ty1 - ty0);
    float w  = fmaxf(fminf(px1, tx1) - fmaxf(px0, tx0), 0.f);
    float h  = fmaxf(fminf(py1, ty1) - fmaxf(py0, ty0), 0.f);
    float inter = w * h;
    float uni   = pa + ta - inter;
    float iou   = inter / uni;            // correctly-rounded IEEE div
    float ew = fmaxf(fmaxf(px1, tx1) - fminf(px0, tx0), 0.f);
    float eh = fmaxf(fmaxf(py1, ty1) - fminf(py0, ty0), 0.f);
    float ea = ew * eh;
    return iou - (ea - uni) / ea;         // correctly-rounded IEEE div
}

__global__ __launch_bounds__(256) void matcher_scan_kernel(
    const float* __restrict__ pred,       // [B,N,4] cxcywh
    const float* __restrict__ tgt,        // [B,T,4] cxcywh
    float* __restrict__ pbest,            // [NSPLIT][B*T]
    float* __restrict__ psec,             // [NSPLIT][B*T]
    int*   __restrict__ pidx)             // [NSPLIT][B*T]
{
    __shared__ float4 sp[NPB];            // pred xyxy
    __shared__ float  spa[NPB];           // pred area
    __shared__ float  rbv[256], rsv[256];
    __shared__ int    riv[256];

    const int ns  = blockIdx.x % NSPLIT;
    const int tc  = (blockIdx.x / NSPLIT) % TBLOCKS;
    const int b   = blockIdx.x / (NSPLIT * TBLOCKS);
    const int tid = threadIdx.x;
    const int tl  = tid & 63;
    const int ng  = tid >> 6;
    const int t   = tc * TCHUNK + tl;

    if (tid < NPB) {
        const float4 pb = ((const float4*)pred)[b * NN + ns * NPB + tid];
        float4 q;
        q.x = pb.x - 0.5f * pb.z;
        q.y = pb.y - 0.5f * pb.w;
        q.z = pb.x + 0.5f * pb.z;
        q.w = pb.y + 0.5f * pb.w;
        sp[tid]  = q;
        spa[tid] = (q.z - q.x) * (q.w - q.y);
    }
    __syncthreads();

    float tx0 = 0.f, ty0 = 0.f, tx1 = 0.f, ty1 = 0.f, ta = 0.f;
    if (t < TT) {
        const float4 tb = ((const float4*)tgt)[b * TT + t];
        tx0 = tb.x - 0.5f * tb.z;
        ty0 = tb.y - 0.5f * tb.w;
        tx1 = tb.x + 0.5f * tb.z;
        ty1 = tb.y + 0.5f * tb.w;
        ta  = (tx1 - tx0) * (ty1 - ty0);
    }

    float best = -INFINITY, second = -INFINITY;
    int   bidx = 0;
    const int k0 = ng * NPW;
    #pragma unroll 5
    for (int k = 0; k < NPW; ++k) {
        const float4 p = sp[k0 + k];      // wave-uniform -> LDS broadcast
        const float pa = spa[k0 + k];

        const float w   = fmaxf(fminf(p.z, tx1) - fmaxf(p.x, tx0), 0.f);
        const float h   = fmaxf(fminf(p.w, ty1) - fmaxf(p.y, ty0), 0.f);
        const float inter = w * h;
        const float uni   = pa + ta - inter;

        const float ew = fmaxf(p.z, tx1) - fminf(p.x, tx0);  // >= 0 always
        const float eh = fmaxf(p.w, ty1) - fminf(p.y, ty0);  // >= 0 always
        const float ea = ew * eh;

        // g = inter/uni - (ea-uni)/ea  ==  (inter*ea + uni*(uni-ea))/(uni*ea)
        const float num = fmaf(inter, ea, uni * (uni - ea));
        const float g   = num * __builtin_amdgcn_rcpf(uni * ea);

        second = __builtin_amdgcn_fmed3f(g, best, second);  // new 2nd-max
        if (g > best) { bidx = k0 + k; }
        best = fmaxf(best, g);
    }

    rbv[tid] = best; rsv[tid] = second; riv[tid] = bidx;
    __syncthreads();

    if (ng == 0 && t < TT) {
        for (int s = 1; s < 4; ++s) {     // ascending wave = ascending n
            const float ob = rbv[s * 64 + tl];
            const float os = rsv[s * 64 + tl];
            const int   oi = riv[s * 64 + tl];
            second = fmaxf(fminf(best, ob), fmaxf(second, os));
            if (ob > best) { best = ob; bidx = oi; }
        }
        const int bt = b * TT + t;
        pbest[ns * BB * TT + bt] = best;
        psec [ns * BB * TT + bt] = second;
        pidx [ns * BB * TT + bt] = ns * NPB + bidx;   // global pred index
    }
}

__global__ __launch_bounds__(256) void matcher_finish_kernel(
    const float* __restrict__ pbest,
    const float* __restrict__ psec,
    const int*   __restrict__ pidx,
    const float* __restrict__ pred,
    const float* __restrict__ tgt,
    const unsigned char* __restrict__ mask,
    float* __restrict__ out)
{
    __shared__ int sflag[256];
    __shared__ int scount;

    const int tid = threadIdx.x;
    const int bt  = blockIdx.x * 256 + tid;   // grid covers exactly B*T
    if (tid == 0) scount = 0;
    __syncthreads();

    float best = -INFINITY, second = -INFINITY;
    int   bidx = 0;
    for (int s = 0; s < NSPLIT; ++s) {        // ascending ns = ascending n
        const float ob = pbest[s * BB * TT + bt];
        const float os = psec [s * BB * TT + bt];
        const int   oi = pidx [s * BB * TT + bt];
        second = fmaxf(fminf(best, ob), fmaxf(second, os));
        if (ob > best) { best = ob; bidx = oi; }
    }

    if (best - second > MARGIN) {
        // approx argmax provably exact; recompute winner's GIoU bit-exactly
        const int b = bt / TT;
        const float4 pb = ((const float4*)pred)[b * NN + bidx];
        const float4 tb = ((const float4*)tgt)[bt];
        const float g = giou_exact(pb, tb);
        const bool valid = (mask[bt] != 0) && (g >= 0.5f);
        out[bt]               = (float)bidx;
        out[BB * TT + bt]     = valid ? 1.f : 0.f;
        out[2 * BB * TT + bt] = g;
    } else {
        const int pos = atomicAdd(&scount, 1);
        sflag[pos] = tid;
    }
    __syncthreads();

    // cooperative exact rescan of ambiguous targets: one wave per entry
    const int cnt  = scount;
    const int lane = tid & 63;
    const int ng   = tid >> 6;
    for (int f = ng; f < cnt; f += 4) {
        const int fbt = blockIdx.x * 256 + sflag[f];
        const int b   = fbt / TT;
        const float4 tb = ((const float4*)tgt)[fbt];

        float bestx = -INFINITY;
        int   bix   = NN;
        for (int n = lane; n < NN; n += 64) {   // ascending n per lane
            const float4 pb = ((const float4*)pred)[b * NN + n];
            const float g = giou_exact(pb, tb);
            if (g > bestx) { bestx = g; bix = n; }
        }
        // cross-lane reduce: max g, lowest n on bit-ties (numpy first-occ.)
        for (int off = 32; off >= 1; off >>= 1) {
            const float ob = __shfl_xor(bestx, off);
            const int   oi = __shfl_xor(bix, off);
            if (ob > bestx || (ob == bestx && oi < bix)) { bestx = ob; bix = oi; }
        }
        if (lane == 0) {
            const bool valid = (mask[fbt] != 0) && (bestx >= 0.5f);
            out[fbt]               = (float)bix;
            out[BB * TT + fbt]     = valid ? 1.f : 0.f;
            out[2 * BB * TT + fbt] = bestx;
        }
    }
}

extern "C" void kernel_launch(void* const* d_in, const int* in_sizes, int n_in,
                              void* d_out, int out_size, void* d_ws, size_t ws_size,
                              hipStream_t stream) {
    const float* pred = (const float*)d_in[0];
    const float* tgt  = (const float*)d_in[1];
    const unsigned char* mask = (const unsigned char*)d_in[2];
    float* out = (float*)d_out;

    const size_t seg = (size_t)NSPLIT * BB * TT * 4;   // 1.3824 MB per array
    char* ws = (char*)d_ws;
    float* pbest = (float*)ws;
    float* psec  = (float*)(ws + seg);
    int*   pidx  = (int*)  (ws + 2 * seg);             // total ~4.15 MB

    matcher_scan_kernel<<<dim3(BB * TBLOCKS * NSPLIT), dim3(256), 0, stream>>>(
        pred, tgt, pbest, psec, pidx);
    matcher_finish_kernel<<<dim3(BB * TT / 256), dim3(256), 0, stream>>>(
        pbest, psec, pidx, pred, tgt, mask, out);
}

// Round 5
// 93.737 us; speedup vs baseline: 1.2468x; 1.0197x over previous
//
#include <hip/hip_runtime.h>

// SimpleMatcher: B=128, N=900 preds, T=300 targets.
// out = [pred_idx (B*T), valid (B*T), max_iou (B*T)] as float.
//
// R5: fixed cost exposed by rocprof: harness's 268MB 0xAA ws-poison fill
// (~41us @6.6TB/s) is inside the timed window -> untouchable floor.
// Controllable part = scan + finish. Changes vs R4:
//  - NSPLIT 9->5 (NPW=45), grid 3200, __launch_bounds__(256,8) (VGPR<=64)
//  - #pragma unroll 9: LDS offsets become immediates, loop ctrl amortized
//  - argmax tracks LOCAL k (0..44): v_cndmask with inline const, +k0 once
// Numerics unchanged: g = (inter*ea + uni*(uni-ea)) * rcp(uni*ea), abs err
// <= ~4e-7 (both num terms <= den); MARGIN 2e-5 -> approx argmax provably
// exact when best-second > MARGIN; winner recomputed bit-exactly; ambiguous
// targets exhaustively rescanned with IEEE math + first-occurrence ties.

#define BB 128
#define NN 900
#define TT 300
#define TCHUNK 64      // targets per block (64 lanes)
#define TBLOCKS 5      // ceil(TT / TCHUNK)
#define NSPLIT 5       // n-splits across blocks
#define NPB 180        // preds per block  (NN / NSPLIT)
#define NPW 45         // preds per wave   (NPB / 4)
#define MARGIN 2e-5f

// Bit-exact GIoU in numpy's exact expression order.
__device__ __forceinline__ float giou_exact(float4 pb, float4 tb) {
#pragma clang fp contract(off)
    float px0 = pb.x - 0.5f * pb.z, py0 = pb.y - 0.5f * pb.w;
    float px1 = pb.x + 0.5f * pb.z, py1 = pb.y + 0.5f * pb.w;
    float tx0 = tb.x - 0.5f * tb.z, ty0 = tb.y - 0.5f * tb.w;
    float tx1 = tb.x + 0.5f * tb.z, ty1 = tb.y + 0.5f * tb.w;
    float pa = (px1 - px0) * (py1 - py0);
    float ta = (tx1 - tx0) * (ty1 - ty0);
    float w  = fmaxf(fminf(px1, tx1) - fmaxf(px0, tx0), 0.f);
    float h  = fmaxf(fminf(py1, ty1) - fmaxf(py0, ty0), 0.f);
    float inter = w * h;
    float uni   = pa + ta - inter;
    float iou   = inter / uni;            // correctly-rounded IEEE div
    float ew = fmaxf(fmaxf(px1, tx1) - fminf(px0, tx0), 0.f);
    float eh = fmaxf(fmaxf(py1, ty1) - fminf(py0, ty0), 0.f);
    float ea = ew * eh;
    return iou - (ea - uni) / ea;         // correctly-rounded IEEE div
}

__global__ __launch_bounds__(256, 8) void matcher_scan_kernel(
    const float* __restrict__ pred,       // [B,N,4] cxcywh
    const float* __restrict__ tgt,        // [B,T,4] cxcywh
    float* __restrict__ pbest,            // [NSPLIT][B*T]
    float* __restrict__ psec,             // [NSPLIT][B*T]
    int*   __restrict__ pidx)             // [NSPLIT][B*T]
{
    __shared__ float4 sp[NPB];            // pred xyxy
    __shared__ float  spa[NPB];           // pred area
    __shared__ float  rbv[256], rsv[256];
    __shared__ int    riv[256];

    const int ns  = blockIdx.x % NSPLIT;
    const int tc  = (blockIdx.x / NSPLIT) % TBLOCKS;
    const int b   = blockIdx.x / (NSPLIT * TBLOCKS);
    const int tid = threadIdx.x;
    const int tl  = tid & 63;
    const int ng  = tid >> 6;
    const int t   = tc * TCHUNK + tl;

    if (tid < NPB) {
        const float4 pb = ((const float4*)pred)[b * NN + ns * NPB + tid];
        float4 q;
        q.x = pb.x - 0.5f * pb.z;
        q.y = pb.y - 0.5f * pb.w;
        q.z = pb.x + 0.5f * pb.z;
        q.w = pb.y + 0.5f * pb.w;
        sp[tid]  = q;
        spa[tid] = (q.z - q.x) * (q.w - q.y);
    }
    __syncthreads();

    float tx0 = 0.f, ty0 = 0.f, tx1 = 0.f, ty1 = 0.f, ta = 0.f;
    if (t < TT) {
        const float4 tb = ((const float4*)tgt)[b * TT + t];
        tx0 = tb.x - 0.5f * tb.z;
        ty0 = tb.y - 0.5f * tb.w;
        tx1 = tb.x + 0.5f * tb.z;
        ty1 = tb.y + 0.5f * tb.w;
        ta  = (tx1 - tx0) * (ty1 - ty0);
    }

    float best = -INFINITY, second = -INFINITY;
    int   bidxl = 0;                      // local k: inline-const cndmask
    const int k0 = ng * NPW;
    #pragma unroll 9
    for (int k = 0; k < NPW; ++k) {
        const float4 p = sp[k0 + k];      // wave-uniform -> LDS broadcast
        const float pa = spa[k0 + k];

        const float w   = fmaxf(fminf(p.z, tx1) - fmaxf(p.x, tx0), 0.f);
        const float h   = fmaxf(fminf(p.w, ty1) - fmaxf(p.y, ty0), 0.f);
        const float inter = w * h;
        const float uni   = pa + ta - inter;

        const float ew = fmaxf(p.z, tx1) - fminf(p.x, tx0);  // >= 0 always
        const float eh = fmaxf(p.w, ty1) - fminf(p.y, ty0);  // >= 0 always
        const float ea = ew * eh;

        // g = inter/uni - (ea-uni)/ea  ==  (inter*ea + uni*(uni-ea))/(uni*ea)
        const float num = fmaf(inter, ea, uni * (uni - ea));
        const float g   = num * __builtin_amdgcn_rcpf(uni * ea);

        second = __builtin_amdgcn_fmed3f(g, best, second);  // new 2nd-max
        if (g > best) bidxl = k;
        best = fmaxf(best, g);
    }
    int bidx = k0 + bidxl;

    rbv[tid] = best; rsv[tid] = second; riv[tid] = bidx;
    __syncthreads();

    if (ng == 0 && t < TT) {
        for (int s = 1; s < 4; ++s) {     // ascending wave = ascending n
            const float ob = rbv[s * 64 + tl];
            const float os = rsv[s * 64 + tl];
            const int   oi = riv[s * 64 + tl];
            second = fmaxf(fminf(best, ob), fmaxf(second, os));
            if (ob > best) { best = ob; bidx = oi; }
        }
        const int bt = b * TT + t;
        pbest[ns * BB * TT + bt] = best;
        psec [ns * BB * TT + bt] = second;
        pidx [ns * BB * TT + bt] = ns * NPB + bidx;   // global pred index
    }
}

__global__ __launch_bounds__(256) void matcher_finish_kernel(
    const float* __restrict__ pbest,
    const float* __restrict__ psec,
    const int*   __restrict__ pidx,
    const float* __restrict__ pred,
    const float* __restrict__ tgt,
    const unsigned char* __restrict__ mask,
    float* __restrict__ out)
{
    __shared__ int sflag[256];
    __shared__ int scount;

    const int tid = threadIdx.x;
    const int bt  = blockIdx.x * 256 + tid;   // grid covers exactly B*T
    if (tid == 0) scount = 0;
    __syncthreads();

    float best = -INFINITY, second = -INFINITY;
    int   bidx = 0;
    #pragma unroll
    for (int s = 0; s < NSPLIT; ++s) {        // ascending ns = ascending n
        const float ob = pbest[s * BB * TT + bt];
        const float os = psec [s * BB * TT + bt];
        const int   oi = pidx [s * BB * TT + bt];
        second = fmaxf(fminf(best, ob), fmaxf(second, os));
        if (ob > best) { best = ob; bidx = oi; }
    }

    if (best - second > MARGIN) {
        // approx argmax provably exact; recompute winner's GIoU bit-exactly
        const int b = bt / TT;
        const float4 pb = ((const float4*)pred)[b * NN + bidx];
        const float4 tb = ((const float4*)tgt)[bt];
        const float g = giou_exact(pb, tb);
        const bool valid = (mask[bt] != 0) && (g >= 0.5f);
        out[bt]               = (float)bidx;
        out[BB * TT + bt]     = valid ? 1.f : 0.f;
        out[2 * BB * TT + bt] = g;
    } else {
        const int pos = atomicAdd(&scount, 1);
        sflag[pos] = tid;
    }
    __syncthreads();

    // cooperative exact rescan of ambiguous targets: one wave per entry
    const int cnt  = scount;
    const int lane = tid & 63;
    const int ng   = tid >> 6;
    for (int f = ng; f < cnt; f += 4) {
        const int fbt = blockIdx.x * 256 + sflag[f];
        const int b   = fbt / TT;
        const float4 tb = ((const float4*)tgt)[fbt];

        float bestx = -INFINITY;
        int   bix   = NN;
        for (int n = lane; n < NN; n += 64) {   // ascending n per lane
            const float4 pb = ((const float4*)pred)[b * NN + n];
            const float g = giou_exact(pb, tb);
            if (g > bestx) { bestx = g; bix = n; }
        }
        // cross-lane reduce: max g, lowest n on bit-ties (numpy first-occ.)
        for (int off = 32; off >= 1; off >>= 1) {
            const float ob = __shfl_xor(bestx, off);
            const int   oi = __shfl_xor(bix, off);
            if (ob > bestx || (ob == bestx && oi < bix)) { bestx = ob; bix = oi; }
        }
        if (lane == 0) {
            const bool valid = (mask[fbt] != 0) && (bestx >= 0.5f);
            out[fbt]               = (float)bix;
            out[BB * TT + fbt]     = valid ? 1.f : 0.f;
            out[2 * BB * TT + fbt] = bestx;
        }
    }
}

extern "C" void kernel_launch(void* const* d_in, const int* in_sizes, int n_in,
                              void* d_out, int out_size, void* d_ws, size_t ws_size,
                              hipStream_t stream) {
    const float* pred = (const float*)d_in[0];
    const float* tgt  = (const float*)d_in[1];
    const unsigned char* mask = (const unsigned char*)d_in[2];
    float* out = (float*)d_out;

    const size_t seg = (size_t)NSPLIT * BB * TT * 4;   // 768 KB per array
    char* ws = (char*)d_ws;
    float* pbest = (float*)ws;
    float* psec  = (float*)(ws + seg);
    int*   pidx  = (int*)  (ws + 2 * seg);             // total ~2.3 MB

    matcher_scan_kernel<<<dim3(BB * TBLOCKS * NSPLIT), dim3(256), 0, stream>>>(
        pred, tgt, pbest, psec, pidx);
    matcher_finish_kernel<<<dim3(BB * TT / 256), dim3(256), 0, stream>>>(
        pbest, psec, pidx, pred, tgt, mask, out);
}